// Round 6
// baseline (122.132 us; speedup 1.0000x reference)
//
#include <hip/hip_runtime.h>

#define N2 128
#define MM 16384
#define START 6
#define BT 128        // 2 waves/block, 16 cols/wave -> 32 cols/block, 512 blocks
#define PZROWS 132    // predZ: rows 0..3 zero (j<0), row 4+j for j=0..127
#define FROWS 152     // fTd: row 16+d; zero for d<2, d<-16..  and d>127
#define STRD 17       // row stride in floats: <=2-way banks everywhere

__global__ __launch_bounds__(BT, 1) void npi_fused(
    const float* __restrict__ rt, const float* __restrict__ dgt,
    const float* __restrict__ si, const float* __restrict__ f,
    const float* __restrict__ seed, float* __restrict__ out)
{
    __shared__ float predZ[2][PZROWS * STRD];   // wave-private tiles
    __shared__ float fTd[2][FROWS * STRD];
    __shared__ float si_s[2][N2];
    __shared__ float wred[2];

    const int t = threadIdx.x;
    const int wv = t >> 6;
    const int l = t & 63;          // lane
    const int a = t & 3;           // team lane (j-class / row-owner)
    const int q = (t >> 2) & 15;   // column within wave
    const int m = blockIdx.x * 32 + wv * 16 + q;

    float* PZ = predZ[wv];
    float* FT = fTd[wv];
    float* SS = si_s[wv];

    // ---- wave-private staging: si copy, zero pads (no barriers needed) ----
    SS[l] = si[l];
    SS[l + 64] = si[l + 64];
    PZ[l] = 0.f;                               // predZ rows 0..3 = floats 0..67
    if (l < 4) PZ[64 + l] = 0.f;
#pragma unroll
    for (int z = 0; z < 5; ++z) {              // fTd rows 0..17: floats [0,306)
        int idx = l + (z << 6);
        if (idx < 18 * STRD) FT[idx] = 0.f;
    }
#pragma unroll
    for (int z = 0; z < 3; ++z) {              // fTd rows 144..151: 136 floats
        int idx = l + (z << 6);
        if (idx < 8 * STRD) FT[144 * STRD + idx] = 0.f;
    }

    // f for this lane's rows -> registers; loads stream under all of phase 1.
    float fregs[32];
#pragma unroll
    for (int rr = 0; rr < 32; ++rr)
        fregs[rr] = f[((rr << 2) + a) * MM + m];

    // chunk-0 inputs
    float rt0[16];
#pragma unroll
    for (int k = 0; k < 16; ++k) rt0[k] = rt[k * MM + m];
    float sd[START];
#pragma unroll
    for (int k = 0; k < START; ++k) sd[k] = seed[k * MM + m];

    __builtin_amdgcn_wave_barrier();

    float sr[16];
#pragma unroll
    for (int k = 1; k < 16; ++k) sr[k] = SS[k];

    // ---- phase 1, chunk 0: seeds + triangle (redundant per team lane) ----
    {
        float p_[16], v[16];
#pragma unroll
        for (int k = 0; k < 16; ++k) p_[k] = 0.f;
#pragma unroll
        for (int k = 0; k < 16; ++k) {
            float vk;
            if (k < START) vk = sd[k];
            else vk = rt0[k] * (p_[k] + sr[1] * v[k - 1]);
            v[k] = vk;
#pragma unroll
            for (int k2 = k + 2; k2 < 16; ++k2)
                p_[k2] += sr[k2 - k] * vk;
        }
#pragma unroll
        for (int r = 0; r < 4; ++r)            // owner lane a writes rows 4a+r
            PZ[(4 + (a << 2) + r) * STRD + q] = v[(a << 2) + r];
    }
    __builtin_amdgcn_wave_barrier();

    // ---- phase 1, chunks b = 1..7 ----
    for (int b = 1; b < 8; ++b) {
        const int i0 = b << 4;
        float rtv[16];
#pragma unroll
        for (int k = 0; k < 16; ++k) rtv[k] = rt[(i0 + k) * MM + m];

        const int nj = b << 2;                 // steps per lane
        const int jtop = nj * (a + 1) - 1;     // lane covers j in [nj*a, nj*(a+1))
        const int base = i0 - jtop;            // si index at (u=0,k=0), >= 1
        float c16[16];
#pragma unroll
        for (int s = 0; s < 16; ++s) c16[s] = SS[base + s];
        float acc[16];
#pragma unroll
        for (int k = 0; k < 16; ++k) acc[k] = 0.f;
#pragma unroll
        for (int u = 0; u < 28; ++u) {
            if (u < nj) {                      // uniform (b) -> scalar branch
                float pv = PZ[(4 + jtop - u) * STRD + q];
#pragma unroll
                for (int k = 0; k < 16; ++k)
                    acc[k] += pv * c16[(u + k) & 15];
                if (u + 1 < nj) c16[u & 15] = SS[base + 16 + u];  // <= 127
            }
        }
#pragma unroll
        for (int k = 0; k < 16; ++k) {
            acc[k] += __shfl_xor(acc[k], 1, 64);
            acc[k] += __shfl_xor(acc[k], 2, 64);
        }
        // triangle, low-latency form (redundant per team lane)
        float p_[16], v[16];
#pragma unroll
        for (int k = 0; k < 16; ++k) p_[k] = acc[k];
#pragma unroll
        for (int k = 0; k < 16; ++k) {
            float vk = (k == 0) ? (rtv[0] * p_[0])
                                : (rtv[k] * (p_[k] + sr[1] * v[k - 1]));
            v[k] = vk;
#pragma unroll
            for (int k2 = k + 2; k2 < 16; ++k2)
                p_[k2] += sr[k2 - k] * vk;
        }
#pragma unroll
        for (int r = 0; r < 4; ++r)
            PZ[(4 + i0 + (a << 2) + r) * STRD + q] = v[(a << 2) + r];
        __builtin_amdgcn_wave_barrier();
    }

    // ---- stage f -> fTd (loads long since landed); rows 16,17 forced 0 ----
#pragma unroll
    for (int rr = 0; rr < 32; ++rr) {
        int r = (rr << 2) + a;
        FT[(16 + r) * STRD + q] = (r < 2) ? 0.f : fregs[rr];
    }
    __builtin_amdgcn_wave_barrier();

    // ---- phase 2: deaths conv + MSE ----
    float lsum = 0.f;
    for (int cc = 0; cc < 8; ++cc) {
        const int i0 = cc << 4;
        const int S = (i0 + 17) >> 2;          // uniform steps per lane
        const int jhi = (i0 + 14) - (3 - a) * S;
        const int bidx = 3 + (3 - a) * S;      // fTd ring base (>= 3)
        float dgv[4];
#pragma unroll
        for (int r = 0; r < 4; ++r)
            dgv[r] = dgt[(i0 + (a << 2) + r) * MM + m];

        float c16[16];
#pragma unroll
        for (int s = 0; s < 16; ++s) c16[s] = FT[(bidx + s) * STRD + q];
        float acc[16];
#pragma unroll
        for (int k = 0; k < 16; ++k) acc[k] = 0.f;
#pragma unroll
        for (int u = 0; u < 32; ++u) {
            if (u < S) {                       // uniform -> scalar branch
                float pv = PZ[(4 + jhi - 1 - u) * STRD + q];  // pad rows = 0
#pragma unroll
                for (int k = 0; k < 16; ++k)
                    acc[k] += pv * c16[(u + k) & 15];
                if (u + 1 < S) c16[u & 15] = FT[(bidx + 16 + u) * STRD + q];
            }
        }
#pragma unroll
        for (int k = 0; k < 16; ++k) {
            acc[k] += __shfl_xor(acc[k], 1, 64);
            acc[k] += __shfl_xor(acc[k], 2, 64);
        }
#pragma unroll
        for (int r = 0; r < 4; ++r) {          // owner rows k = 4a+r
            int k = (a << 2) + r;
            float e = acc[k];
            if (cc == 0 && k < START) e = (k == 0) ? 1e-9f : 0.f;
            float d = e - dgv[r];
            lsum += d * d;
        }
    }

    // ---- loss: wave shuffle-reduce, tiny block fold, 1 atomic/block ----
#pragma unroll
    for (int off = 32; off > 0; off >>= 1)
        lsum += __shfl_down(lsum, off, 64);
    if (l == 0) wred[wv] = lsum;
    __syncthreads();
    if (t == 0)
        atomicAdd(out, (wred[0] + wred[1]) * (1.0f / ((float)N2 * (float)MM)));
}

extern "C" void kernel_launch(void* const* d_in, const int* in_sizes, int n_in,
                              void* d_out, int out_size, void* d_ws, size_t ws_size,
                              hipStream_t stream) {
    const float* rt   = (const float*)d_in[0];
    const float* dgt  = (const float*)d_in[1];
    const float* si   = (const float*)d_in[2];
    const float* f    = (const float*)d_in[3];
    const float* seed = (const float*)d_in[4];

    hipMemsetAsync(d_out, 0, sizeof(float), stream);
    npi_fused<<<dim3(512), dim3(BT), 0, stream>>>(
        rt, dgt, si, f, seed, (float*)d_out);
}

// Round 7
// 107.057 us; speedup vs baseline: 1.1408x; 1.1408x over previous
//
#include <hip/hip_runtime.h>

#define N2 128
#define MM 16384
#define START 6
#define CB 32        // columns per block -> 512 blocks
#define BT 256       // 4 waves = 8 half-wave shares (32 lanes each)
#define PROWS 132    // predT rows: 0..127 data, 128..131 zero
#define FROWS 152    // fTd rows: index = 16 + d; zero outside d in [2,127]

__global__ __launch_bounds__(BT, 4) void npi_fused(
    const float* __restrict__ rt, const float* __restrict__ dgt,
    const float* __restrict__ si, const float* __restrict__ f,
    const float* __restrict__ seed, float* __restrict__ out)
{
    __shared__ float predT[PROWS * CB];    // 16.5 KiB [row][col]
    __shared__ float funion[FROWS * CB];   // 19.0 KiB: part (phase 1) / fTd (phase 2)
    __shared__ float si_s[N2];
    __shared__ float lred[4];
    float* part = funion;                  // rows 0..63 used as [wave][k][col]
    float* fTd  = funion;                  // staged after phase 1

    const int t = threadIdx.x;
    const int c = t & (CB - 1);
    const int w = t >> 6;          // wave 0..3
    const int g = t >> 5;          // half-wave share 0..7
    const int hw = g & 1;          // half within wave
    const int m = blockIdx.x * CB + c;

    // f rows for this share -> registers; loads stream under all of phase 1.
    float fregs[16];
#pragma unroll
    for (int q = 0; q < 16; ++q)
        fregs[q] = f[((g << 4) + q) * MM + m];

    if (t < N2) si_s[t] = si[t];
    if (g < START) predT[(g << 5) + c] = seed[g * MM + m];
    if (g < 4) predT[((128 + g) << 5) + c] = 0.f;   // pred pad rows 128..131

    float r16v[16];
#pragma unroll
    for (int k = 0; k < 16; ++k)
        r16v[k] = rt[k * MM + m];                   // chunk-0 rows

    __syncthreads();

    float sr[16];
#pragma unroll
    for (int k = 1; k < 16; ++k) sr[k] = si_s[k];

    // ---- phase 1, chunk 0: triangle from seeds (redundant per wave) ----
    {
        float p_[16], v[16];
#pragma unroll
        for (int k = 0; k < 16; ++k) p_[k] = 0.f;
#pragma unroll
        for (int k = 0; k < 16; ++k) {
            float vk;
            if (k < START) vk = predT[(k << 5) + c];
            else vk = r16v[k] * (p_[k] + sr[1] * v[k - 1]);
            v[k] = vk;
#pragma unroll
            for (int k2 = k + 2; k2 < 16; ++k2)
                p_[k2] += sr[k2 - k] * vk;
        }
        if (w == 3 && hw == 0) {
#pragma unroll
            for (int k = START; k < 16; ++k) predT[(k << 5) + c] = v[k];
        }
    }
    __syncthreads();

    // ---- phase 1, chunks b = 1..7: 8 equal j-shares of 2b each ----
    for (int b = 1; b < 8; ++b) {
        const int i0 = b << 4;
        const int nst = b << 1;                   // steps per share (<= 14)
#pragma unroll
        for (int k = 0; k < 16; ++k)
            r16v[k] = rt[(i0 + k) * MM + m];      // prefetch for triangle

        const int jhi = nst * (g + 1);            // share j in [jhi-nst, jhi)
        const int base = i0 - jhi + 1;            // >= 1
        float c16[16];
#pragma unroll
        for (int e = 0; e < 16; ++e) c16[e] = si_s[base + e];
        float acc[16];
#pragma unroll
        for (int k = 0; k < 16; ++k) acc[k] = 0.f;
#pragma unroll
        for (int u = 0; u < 14; ++u) {            // nst <= 14; uniform guard
            if (u < nst) {
                float p = predT[((jhi - 1 - u) << 5) + c];
#pragma unroll
                for (int k = 0; k < 16; ++k)
                    acc[k] += p * c16[(u + k) & 15];
                if (u + 1 < nst) c16[u & 15] = si_s[base + 16 + u];  // <=127
            }
        }
        // fold the two shares of each wave (free, in-register)
#pragma unroll
        for (int k = 0; k < 16; ++k)
            acc[k] += __shfl_xor(acc[k], 32, 64);
        if (hw == 0) {
#pragma unroll
            for (int k = 0; k < 16; ++k)
                part[(((w << 4) + k) << 5) + c] = acc[k];
        }
        __syncthreads();

        // reduce 4 wave-partials + short-chain triangle (redundant per wave)
        float p_[16], v[16];
#pragma unroll
        for (int k = 0; k < 16; ++k)
            p_[k] = part[(k << 5) + c] + part[((16 + k) << 5) + c]
                  + part[((32 + k) << 5) + c] + part[((48 + k) << 5) + c];
#pragma unroll
        for (int k = 0; k < 16; ++k) {
            float vk = (k == 0) ? (r16v[0] * p_[0])
                                : (r16v[k] * (p_[k] + sr[1] * v[k - 1]));
            v[k] = vk;
#pragma unroll
            for (int k2 = k + 2; k2 < 16; ++k2)
                p_[k2] += sr[k2 - k] * vk;
        }
        // wave w writes rows [i0+4w, i0+4w+4), 2 rows per half-wave
        {
            float a0, a1;
            if (w == 0)      { a0 = hw ? v[2]  : v[0];  a1 = hw ? v[3]  : v[1];  }
            else if (w == 1) { a0 = hw ? v[6]  : v[4];  a1 = hw ? v[7]  : v[5];  }
            else if (w == 2) { a0 = hw ? v[10] : v[8];  a1 = hw ? v[11] : v[9];  }
            else             { a0 = hw ? v[14] : v[12]; a1 = hw ? v[15] : v[13]; }
            const int r0 = i0 + (w << 2) + (hw << 1);
            predT[(r0 << 5) + c] = a0;
            predT[((r0 + 1) << 5) + c] = a1;
        }
        __syncthreads();
    }

    // ---- stage f -> fTd (part is dead now); zero the pad rows too ----
#pragma unroll
    for (int q = 0; q < 16; ++q) {
        int d = (g << 4) + q;
        fTd[((16 + d) << 5) + c] = (d < 2) ? 0.f : fregs[q];
    }
    fTd[((g << 1) << 5) + c] = 0.f;               // rows 0..15 (2 per share)
    fTd[(((g << 1) + 1) << 5) + c] = 0.f;
    fTd[((144 + g) << 5) + c] = 0.f;              // rows 144..151
    __syncthreads();

    // ---- phase 2: deaths conv + MSE ----
    float lsum = 0.f;
    if (hw == 0) {
        float dv = dgt[w * MM + m];
        float e0 = (w == 0) ? (1e-9f - dv) : dv;
        lsum += e0 * e0;
        if (w < 2) {
            float d2 = dgt[(4 + w) * MM + m];
            lsum += d2 * d2;
        }
    }

#pragma unroll
    for (int pass = 0; pass < 2; ++pass) {
        const int n = pass ? (7 - w) : w;         // pairs {n, 7-n}: balanced
        const int i0 = START + (n << 4);          // 6..118
        const int jhi2 = i0 + 14;                 // even
        const int steps = jhi2 >> 1;              // equal per half (<= 66)
        const int jh = hw ? jhi2 : (jhi2 >> 1);   // this half's j-range top
        const int fb = 17 + i0 - jh;              // ring base index into fTd

        float dg[16];
#pragma unroll
        for (int k = 0; k < 16; ++k)
            dg[k] = (i0 + k < N2) ? dgt[(i0 + k) * MM + m] : 0.f;

        float cf[16];
#pragma unroll
        for (int e = 0; e < 16; ++e) cf[e] = fTd[((fb + e) << 5) + c];
        float acc[16];
#pragma unroll
        for (int k = 0; k < 16; ++k) acc[k] = 0.f;

        for (int sb = 0; sb < steps; sb += 16) {
#pragma unroll
            for (int u = 0; u < 16; ++u) {
                int s = sb + u;
                if (s < steps) {                  // uniform guard
                    float p = predT[((jh - 1 - s) << 5) + c];  // pad rows = 0
#pragma unroll
                    for (int k = 0; k < 16; ++k)
                        acc[k] += p * cf[(u + k) & 15];
                    cf[u] = fTd[((fb + 16 + s) << 5) + c];     // max idx 150
                }
            }
        }
#pragma unroll
        for (int k = 0; k < 16; ++k)
            acc[k] += __shfl_xor(acc[k], 32, 64);
        if (hw == 0) {
#pragma unroll
            for (int k = 0; k < 16; ++k) {
                if (i0 + k < N2) {
                    float diff = acc[k] - dg[k];
                    lsum += diff * diff;
                }
            }
        }
    }

    // ---- loss reduction ----
#pragma unroll
    for (int off = 32; off > 0; off >>= 1)
        lsum += __shfl_down(lsum, off, 64);
    if ((t & 63) == 0) lred[w] = lsum;
    __syncthreads();
    if (t == 0)
        atomicAdd(out, (lred[0] + lred[1] + lred[2] + lred[3]) *
                       (1.0f / ((float)N2 * (float)MM)));
}

extern "C" void kernel_launch(void* const* d_in, const int* in_sizes, int n_in,
                              void* d_out, int out_size, void* d_ws, size_t ws_size,
                              hipStream_t stream) {
    const float* rt   = (const float*)d_in[0];
    const float* dgt  = (const float*)d_in[1];
    const float* si   = (const float*)d_in[2];
    const float* f    = (const float*)d_in[3];
    const float* seed = (const float*)d_in[4];

    hipMemsetAsync(d_out, 0, sizeof(float), stream);
    npi_fused<<<dim3(MM / CB), dim3(BT), 0, stream>>>(
        rt, dgt, si, f, seed, (float*)d_out);
}